// Round 1
// 565.379 us; speedup vs baseline: 1.0062x; 1.0062x over previous
//
#include <hip/hip_runtime.h>
#include <hip/hip_bf16.h>

typedef __bf16 bf16;
typedef __bf16 bf16x8 __attribute__((ext_vector_type(8)));
typedef float  f32x4  __attribute__((ext_vector_type(4)));

#define M_DIM 8192
#define N_DIM 4096
#define K_DIM 4096
#define NT    (K_DIM / 64)   // 64 K-tiles of BK=64

#define GLOBAL_AS __attribute__((address_space(1)))
#define LDS_AS    __attribute__((address_space(3)))

// ---------------- conversion kernels (32 B in / 16 B out per thread) ----------------

__global__ __launch_bounds__(256) void cvt_input_bf16(const float4* __restrict__ in,
                                                      bf16x8* __restrict__ out) {
    int idx = blockIdx.x * 256 + threadIdx.x;
    float4 v0 = in[2 * idx];
    float4 v1 = in[2 * idx + 1];
    bf16x8 o;
    o[0] = (bf16)v0.x; o[1] = (bf16)v0.y; o[2] = (bf16)v0.z; o[3] = (bf16)v0.w;
    o[4] = (bf16)v1.x; o[5] = (bf16)v1.y; o[6] = (bf16)v1.z; o[7] = (bf16)v1.w;
    out[idx] = o;
}

__global__ __launch_bounds__(256) void cvt_weight_bf16(const int4* __restrict__ in,
                                                       bf16x8* __restrict__ out) {
    int idx = blockIdx.x * 256 + threadIdx.x;
    int4 v0 = in[2 * idx];
    int4 v1 = in[2 * idx + 1];
    bf16x8 o;
    o[0] = (bf16)(float)v0.x; o[1] = (bf16)(float)v0.y;
    o[2] = (bf16)(float)v0.z; o[3] = (bf16)(float)v0.w;
    o[4] = (bf16)(float)v1.x; o[5] = (bf16)(float)v1.y;
    o[6] = (bf16)(float)v1.z; o[7] = (bf16)(float)v1.w;
    out[idx] = o;
}

// ---------------- main GEMM: 256x256 tile, BK=64, 8-phase schedule (m201 structure) ----
// C[m][n] = sum_k A[m][k]*B[n][k].  8 waves (2M x 4N), each owns 128x64 output.
// LDS: A,B tiles [256][64] bf16, double-buffered = 128 KiB.
//
// Swizzle (T2): within a 128 B row, 16 B chunk c stored at phys chunk c^(row&7).
// Staged by pre-swizzling the GLOBAL source column per lane (LDS dest stays
// linear, as global_load_lds requires); ds_read applies the same XOR.
//
// Pipeline (T3/T4): per K-tile t (buf s=t&1), 4 phases; each phase = {ds_read
// subtile; stage 1 half-tile; barrier; lgkmcnt(0); setprio(1); 16 MFMA;
// setprio(0); barrier}.  Stage order: ph1: t+1.A1 -> s^1; ph2: t+1.B1 -> s^1;
// ph3: t+2.B0 -> s; ph4: t+2.A0 -> s.  Region-retirement proof: B0(s) last
// read ph2 (waves wn<2), staged ph3; A0(s) last read ph3 (waves wm=0, mh1),
// staged ph4; each separated by a barrier from the overwrite issue.
// vmcnt(4) once per tile at ph4 (12 outstanding -> 4 = next tile's B0,A0 in
// flight); never drained to 0 in the loop.

__global__ __launch_bounds__(512, 2) void gemm_bt_256(const bf16* __restrict__ A,
                                                      const bf16* __restrict__ B,
                                                      const float* __restrict__ scales,
                                                      float* __restrict__ C) {
    __shared__ bf16 ldsA[2 * 16384];   // [buf][256][64]
    __shared__ bf16 ldsB[2 * 16384];

    const int tid  = threadIdx.x;
    const int wave = tid >> 6;          // 0..7
    const int lane = tid & 63;
    const int wm   = wave >> 2;         // 0..1  (M)
    const int wn   = wave & 3;          // 0..3  (N)

    // T1: bijective XCD swizzle (gridDim.x = 512, 512 % 8 == 0)
    const int wg  = blockIdx.x;
    const int swz = (wg & 7) * (512 >> 3) + (wg >> 3);
    const int n0  = (swz & 15) * 256;   // N/256 = 16 (fast axis)
    const int m0  = (swz >> 4) * 256;   // M/256 = 32

    // staging addressing: thread t covers phys chunk (t&7) of row (t>>3) [+64 for 2nd load]
    const int sr = tid >> 3;                       // 0..63
    const int sc = ((tid & 7) ^ (sr & 7)) * 8;     // pre-swizzled global col (elems)
    const int so = tid * 8;                        // linear LDS dest (elems)

    // fragment addressing
    const int la15 = lane & 15;
    const int lhi  = lane >> 4;                    // 0..3 -> k-chunk
    const int rlow = la15 & 7;
    const int ck0  = ((lhi) ^ rlow) * 8;           // kh=0 chunk, swizzled
    const int ck1  = ((4 + lhi) ^ rlow) * 8;       // kh=1 chunk, swizzled
    const int wrA  = wm * 128;
    const int wrB  = wn * 64;

    f32x4  acc[8][4] = {};
    bf16x8 af[2][4], b0[2][2], b1[2][2];

#define STAGE_A(KT, H) do {                                                              \
    const int _kk = (KT) & (NT - 1);                                                     \
    const int _bb = ((KT) & 1) * 16384;                                                  \
    const bf16* _g0 = A + (size_t)(m0 + (H) * 128 + sr) * K_DIM + _kk * 64 + sc;         \
    __builtin_amdgcn_global_load_lds((GLOBAL_AS const void*)_g0,                         \
        (LDS_AS void*)(ldsA + _bb + (H) * 8192 + so), 16, 0, 0);                         \
    const bf16* _g1 = A + (size_t)(m0 + (H) * 128 + 64 + sr) * K_DIM + _kk * 64 + sc;    \
    __builtin_amdgcn_global_load_lds((GLOBAL_AS const void*)_g1,                         \
        (LDS_AS void*)(ldsA + _bb + (H) * 8192 + 4096 + so), 16, 0, 0);                  \
} while (0)

#define STAGE_B(KT, H) do {                                                              \
    const int _kk = (KT) & (NT - 1);                                                     \
    const int _bb = ((KT) & 1) * 16384;                                                  \
    const bf16* _g0 = B + (size_t)(n0 + (H) * 128 + sr) * K_DIM + _kk * 64 + sc;         \
    __builtin_amdgcn_global_load_lds((GLOBAL_AS const void*)_g0,                         \
        (LDS_AS void*)(ldsB + _bb + (H) * 8192 + so), 16, 0, 0);                         \
    const bf16* _g1 = B + (size_t)(n0 + (H) * 128 + 64 + sr) * K_DIM + _kk * 64 + sc;    \
    __builtin_amdgcn_global_load_lds((GLOBAL_AS const void*)_g1,                         \
        (LDS_AS void*)(ldsB + _bb + (H) * 8192 + 4096 + so), 16, 0, 0);                  \
} while (0)

#define LDA(MH, BO) do {                                                                 \
    _Pragma("unroll")                                                                    \
    for (int _i = 0; _i < 4; ++_i) {                                                     \
        const int _r = (BO) + (wrA + (MH) * 64 + _i * 16 + la15) * 64;                   \
        af[0][_i] = *(const bf16x8*)(ldsA + _r + ck0);                                   \
        af[1][_i] = *(const bf16x8*)(ldsA + _r + ck1);                                   \
    }                                                                                    \
} while (0)

#define LDB(NH, DST, BO) do {                                                            \
    _Pragma("unroll")                                                                    \
    for (int _j = 0; _j < 2; ++_j) {                                                     \
        const int _r = (BO) + (wrB + (NH) * 32 + _j * 16 + la15) * 64;                   \
        DST[0][_j] = *(const bf16x8*)(ldsB + _r + ck0);                                  \
        DST[1][_j] = *(const bf16x8*)(ldsB + _r + ck1);                                  \
    }                                                                                    \
} while (0)

#define MMA_BLK(I0, J0, BB) do {                                                         \
    __builtin_amdgcn_s_setprio(1);                                                       \
    _Pragma("unroll")                                                                    \
    for (int _i = 0; _i < 4; ++_i) {                                                     \
        _Pragma("unroll")                                                                \
        for (int _j = 0; _j < 2; ++_j) {                                                 \
            acc[(I0) + _i][(J0) + _j] = __builtin_amdgcn_mfma_f32_16x16x32_bf16(         \
                af[0][_i], BB[0][_j], acc[(I0) + _i][(J0) + _j], 0, 0, 0);               \
            acc[(I0) + _i][(J0) + _j] = __builtin_amdgcn_mfma_f32_16x16x32_bf16(         \
                af[1][_i], BB[1][_j], acc[(I0) + _i][(J0) + _j], 0, 0, 0);               \
        }                                                                                \
    }                                                                                    \
    __builtin_amdgcn_s_setprio(0);                                                       \
} while (0)

#define BAR()    __builtin_amdgcn_s_barrier()
#define LGKM0()  do { asm volatile("s_waitcnt lgkmcnt(0)" ::: "memory");                 \
                      __builtin_amdgcn_sched_barrier(0); } while (0)
#define SCHED0() __builtin_amdgcn_sched_barrier(0)

    // ---- prologue: tile0 fully + tile1 {B0,A0} in flight ----
    STAGE_A(0, 0); STAGE_B(0, 0); STAGE_A(0, 1); STAGE_B(0, 1);
    STAGE_B(1, 0); STAGE_A(1, 0);
    asm volatile("s_waitcnt vmcnt(4)" ::: "memory");   // tile0 complete, 4 outstanding
    BAR(); SCHED0();

    for (int t = 0; t < NT; ++t) {
        const int bo = (t & 1) * 16384;

        // ---- phase 1: quadrant (mh0, nh0) ----
        LDA(0, bo);
        LDB(0, b0, bo);
        STAGE_A(t + 1, 1);
        BAR();
        LGKM0();
        MMA_BLK(0, 0, b0);
        BAR(); SCHED0();

        // ---- phase 2: quadrant (mh0, nh1) ----
        LDB(1, b1, bo);
        STAGE_B(t + 1, 1);
        BAR();
        LGKM0();
        MMA_BLK(0, 2, b1);
        BAR(); SCHED0();

        // ---- phase 3: quadrant (mh1, nh1) ----
        LDA(1, bo);
        STAGE_B(t + 2, 0);
        BAR();
        LGKM0();
        MMA_BLK(4, 2, b1);
        BAR(); SCHED0();

        // ---- phase 4: quadrant (mh1, nh0) ----
        STAGE_A(t + 2, 0);
        BAR();
        MMA_BLK(4, 0, b0);
        asm volatile("s_waitcnt vmcnt(4)" ::: "memory");  // next tile fully staged
        BAR(); SCHED0();
    }

    asm volatile("s_waitcnt vmcnt(0)" ::: "memory");  // drain tail stages before exit

    // ---- epilogue: C/D layout col = lane&15 (N), row = (lane>>4)*4 + reg (M) ----
    const int crow = lhi * 4;
#pragma unroll
    for (int j = 0; j < 4; ++j) {
        const int col = n0 + wrB + j * 16 + la15;
        const float s = scales[col];
#pragma unroll
        for (int i = 0; i < 8; ++i) {
            const int rowb = m0 + wrA + i * 16 + crow;
#pragma unroll
            for (int r = 0; r < 4; ++r)
                C[(size_t)(rowb + r) * N_DIM + col] = acc[i][j][r] * s;
        }
    }

#undef STAGE_A
#undef STAGE_B
#undef LDA
#undef LDB
#undef MMA_BLK
#undef BAR
#undef LGKM0
#undef SCHED0
}

// ---------------- fallback: fused conversion staging (no workspace needed) ----------------

__global__ __launch_bounds__(256, 2) void gemm_fused(const float* __restrict__ A,
                                                     const int* __restrict__ B,
                                                     const float* __restrict__ scales,
                                                     float* __restrict__ C) {
    __shared__ bf16 lds_a[128 * 32];
    __shared__ bf16 lds_b[128 * 32];

    const int tid  = threadIdx.x;
    const int wave = tid >> 6;
    const int lane = tid & 63;
    const int m0 = blockIdx.y * 128;
    const int n0 = blockIdx.x * 128;
    const int wm = (wave >> 1) * 64;
    const int wn = (wave & 1) * 64;

    const int sr = tid >> 1;
    const int sc = (tid & 1) * 16;

    const int la = lane & 15;
    const int lk = (lane >> 4) * 8;

    f32x4 acc[4][4] = {};

    for (int k0 = 0; k0 < K_DIM; k0 += 32) {
        __syncthreads();
        {
            const float* ga = A + (size_t)(m0 + sr) * K_DIM + k0 + sc;
            float4 v0 = *(const float4*)(ga + 0);
            float4 v1 = *(const float4*)(ga + 4);
            float4 v2 = *(const float4*)(ga + 8);
            float4 v3 = *(const float4*)(ga + 12);
            bf16x8 p0, p1;
            p0[0]=(bf16)v0.x; p0[1]=(bf16)v0.y; p0[2]=(bf16)v0.z; p0[3]=(bf16)v0.w;
            p0[4]=(bf16)v1.x; p0[5]=(bf16)v1.y; p0[6]=(bf16)v1.z; p0[7]=(bf16)v1.w;
            p1[0]=(bf16)v2.x; p1[1]=(bf16)v2.y; p1[2]=(bf16)v2.z; p1[3]=(bf16)v2.w;
            p1[4]=(bf16)v3.x; p1[5]=(bf16)v3.y; p1[6]=(bf16)v3.z; p1[7]=(bf16)v3.w;
            *(bf16x8*)(lds_a + sr * 32 + sc)     = p0;
            *(bf16x8*)(lds_a + sr * 32 + sc + 8) = p1;
        }
        {
            const int* gb = B + (size_t)(n0 + sr) * K_DIM + k0 + sc;
            int4 v0 = *(const int4*)(gb + 0);
            int4 v1 = *(const int4*)(gb + 4);
            int4 v2 = *(const int4*)(gb + 8);
            int4 v3 = *(const int4*)(gb + 12);
            bf16x8 p0, p1;
            p0[0]=(bf16)(float)v0.x; p0[1]=(bf16)(float)v0.y; p0[2]=(bf16)(float)v0.z; p0[3]=(bf16)(float)v0.w;
            p0[4]=(bf16)(float)v1.x; p0[5]=(bf16)(float)v1.y; p0[6]=(bf16)(float)v1.z; p0[7]=(bf16)(float)v1.w;
            p1[0]=(bf16)(float)v2.x; p1[1]=(bf16)(float)v2.y; p1[2]=(bf16)(float)v2.z; p1[3]=(bf16)(float)v2.w;
            p1[4]=(bf16)(float)v3.x; p1[5]=(bf16)(float)v3.y; p1[6]=(bf16)(float)v3.z; p1[7]=(bf16)(float)v3.w;
            *(bf16x8*)(lds_b + sr * 32 + sc)     = p0;
            *(bf16x8*)(lds_b + sr * 32 + sc + 8) = p1;
        }
        __syncthreads();

        bf16x8 af[4], bfg[4];
#pragma unroll
        for (int i = 0; i < 4; ++i)
            af[i] = *(const bf16x8*)(lds_a + (wm + i * 16 + la) * 32 + lk);
#pragma unroll
        for (int j = 0; j < 4; ++j)
            bfg[j] = *(const bf16x8*)(lds_b + (wn + j * 16 + la) * 32 + lk);
#pragma unroll
        for (int i = 0; i < 4; ++i)
#pragma unroll
            for (int j = 0; j < 4; ++j)
                acc[i][j] = __builtin_amdgcn_mfma_f32_16x16x32_bf16(af[i], bfg[j], acc[i][j], 0, 0, 0);
    }

    const int crow = (lane >> 4) * 4;
#pragma unroll
    for (int j = 0; j < 4; ++j) {
        const int col = n0 + wn + j * 16 + la;
        const float s = scales[col];
#pragma unroll
        for (int i = 0; i < 4; ++i) {
            const int rowb = m0 + wm + i * 16 + crow;
#pragma unroll
            for (int r = 0; r < 4; ++r)
                C[(size_t)(rowb + r) * N_DIM + col] = acc[i][j][r] * s;
        }
    }
}

// ---------------- launch ----------------

extern "C" void kernel_launch(void* const* d_in, const int* in_sizes, int n_in,
                              void* d_out, int out_size, void* d_ws, size_t ws_size,
                              hipStream_t stream) {
    const float* input  = (const float*)d_in[0];   // [M, K] fp32
    const int*   weight = (const int*)d_in[1];     // [N, K] int32 (int8 values)
    const float* scales = (const float*)d_in[2];   // [N] fp32
    float* out = (float*)d_out;                    // [M, N] fp32

    const size_t needA = (size_t)M_DIM * K_DIM * sizeof(bf16);   // 64 MiB
    const size_t needB = (size_t)N_DIM * K_DIM * sizeof(bf16);   // 32 MiB

    if (ws_size >= needA + needB) {
        bf16* Abf = (bf16*)d_ws;
        bf16* Bbf = (bf16*)((char*)d_ws + needA);
        cvt_input_bf16<<<(M_DIM * (size_t)K_DIM / 8) / 256, 256, 0, stream>>>(
            (const float4*)input, (bf16x8*)Abf);
        cvt_weight_bf16<<<(N_DIM * (size_t)K_DIM / 8) / 256, 256, 0, stream>>>(
            (const int4*)weight, (bf16x8*)Bbf);
        gemm_bt_256<<<(M_DIM / 256) * (N_DIM / 256), 512, 0, stream>>>(Abf, Bbf, scales, out);
    } else {
        dim3 grid(N_DIM / 128, M_DIM / 128);
        gemm_fused<<<grid, 256, 0, stream>>>(input, weight, scales, out);
    }
}

// Round 2
// 551.073 us; speedup vs baseline: 1.0324x; 1.0260x over previous
//
#include <hip/hip_runtime.h>
#include <hip/hip_bf16.h>

typedef __bf16 bf16;
typedef __bf16 bf16x8 __attribute__((ext_vector_type(8)));
typedef float  f32x4  __attribute__((ext_vector_type(4)));

#define M_DIM 8192
#define N_DIM 4096
#define K_DIM 4096
#define NT    (K_DIM / 64)   // 64 K-tiles of BK=64

#define GLOBAL_AS __attribute__((address_space(1)))
#define LDS_AS    __attribute__((address_space(3)))

// ---------------- conversion kernels (32 B in / 16 B out per thread) ----------------

__global__ __launch_bounds__(256) void cvt_input_bf16(const float4* __restrict__ in,
                                                      bf16x8* __restrict__ out) {
    int idx = blockIdx.x * 256 + threadIdx.x;
    float4 v0 = in[2 * idx];
    float4 v1 = in[2 * idx + 1];
    bf16x8 o;
    o[0] = (bf16)v0.x; o[1] = (bf16)v0.y; o[2] = (bf16)v0.z; o[3] = (bf16)v0.w;
    o[4] = (bf16)v1.x; o[5] = (bf16)v1.y; o[6] = (bf16)v1.z; o[7] = (bf16)v1.w;
    out[idx] = o;
}

__global__ __launch_bounds__(256) void cvt_weight_bf16(const int4* __restrict__ in,
                                                       bf16x8* __restrict__ out) {
    int idx = blockIdx.x * 256 + threadIdx.x;
    int4 v0 = in[2 * idx];
    int4 v1 = in[2 * idx + 1];
    bf16x8 o;
    o[0] = (bf16)(float)v0.x; o[1] = (bf16)(float)v0.y;
    o[2] = (bf16)(float)v0.z; o[3] = (bf16)(float)v0.w;
    o[4] = (bf16)(float)v1.x; o[5] = (bf16)(float)v1.y;
    o[6] = (bf16)(float)v1.z; o[7] = (bf16)(float)v1.w;
    out[idx] = o;
}

// ---------------- main GEMM: 256x256 tile, BK=64, 8-phase schedule ----------------
// C[m][n] = sum_k A[m][k]*B[n][k].  8 waves (2M x 4N), each owns 128x64 output.
// LDS: A,B tiles [256][64] bf16, double-buffered = 128 KiB.
//
// Swizzle (T2): within a 128 B row, 16 B chunk c stored at phys chunk c^(row&7),
// staged via pre-swizzled GLOBAL source column per lane (LDS dest linear).
//
// Phase interior (round-2 change): NO manual lgkmcnt(0)/sched_barrier pins.
// The compiler emits fine-grained lgkmcnt(N) between ds_read and MFMA and may
// float reads into the preceding MFMA region — the stage-vs-read hazard proof
// only needs: each phase's ds_reads are consumed by that phase's MFMAs before
// the phase-end barrier, and every stage into the live buffer (t+2 B0 at ph3,
// t+2 A0 at ph4) is issued after the barrier that follows its region's last
// consuming MFMA. vmcnt(4) once per tile (counted, never 0 in-loop); its
// "memory" clobber fences next-tile ds_reads behind tile-(t+1) residency.

__global__ __launch_bounds__(512, 2) void gemm_bt_256(const bf16* __restrict__ A,
                                                      const bf16* __restrict__ B,
                                                      const float* __restrict__ scales,
                                                      float* __restrict__ C) {
    __shared__ bf16 ldsA[2 * 16384];   // [buf][256][64]
    __shared__ bf16 ldsB[2 * 16384];

    const int tid  = threadIdx.x;
    const int wave = tid >> 6;          // 0..7
    const int lane = tid & 63;
    const int wm   = wave >> 2;         // 0..1  (M)
    const int wn   = wave & 3;          // 0..3  (N)

    // XCD-stripe mapping (round-2 change): XCD x = wg&7 owns n-columns {2x,2x+1},
    // m-major inside -> the 32 concurrently-resident blocks of an XCD share ONE
    // 2 MiB B panel (fits the 4 MiB per-XCD L2) while streaming A panels.
    const int wg = blockIdx.x;
    const int x  = wg & 7;              // XCD (dispatch round-robins blockIdx%8)
    const int c  = wg >> 3;             // 0..63 within XCD
    const int n0 = (x * 2 + (c >> 5)) * 256;   // 16 n-columns total
    const int m0 = (c & 31) * 256;             // 32 m-rows

    // staging addressing: thread t covers phys chunk (t&7) of row (t>>3) [+64 for 2nd load]
    const int sr = tid >> 3;                       // 0..63
    const int sc = ((tid & 7) ^ (sr & 7)) * 8;     // pre-swizzled global col (elems)
    const int so = tid * 8;                        // linear LDS dest (elems)

    // fragment addressing
    const int la15 = lane & 15;
    const int lhi  = lane >> 4;                    // 0..3 -> k-chunk
    const int rlow = la15 & 7;
    const int ck0  = ((lhi) ^ rlow) * 8;           // kh=0 chunk, swizzled
    const int ck1  = ((4 + lhi) ^ rlow) * 8;       // kh=1 chunk, swizzled
    const int wrA  = wm * 128;
    const int wrB  = wn * 64;

    f32x4  acc[8][4] = {};
    bf16x8 af[2][4], b0[2][2], b1[2][2];

#define STAGE_A(KT, H) do {                                                              \
    const int _kk = (KT) & (NT - 1);                                                     \
    const int _bb = ((KT) & 1) * 16384;                                                  \
    const bf16* _g0 = A + (size_t)(m0 + (H) * 128 + sr) * K_DIM + _kk * 64 + sc;         \
    __builtin_amdgcn_global_load_lds((GLOBAL_AS const void*)_g0,                         \
        (LDS_AS void*)(ldsA + _bb + (H) * 8192 + so), 16, 0, 0);                         \
    const bf16* _g1 = A + (size_t)(m0 + (H) * 128 + 64 + sr) * K_DIM + _kk * 64 + sc;    \
    __builtin_amdgcn_global_load_lds((GLOBAL_AS const void*)_g1,                         \
        (LDS_AS void*)(ldsA + _bb + (H) * 8192 + 4096 + so), 16, 0, 0);                  \
} while (0)

#define STAGE_B(KT, H) do {                                                              \
    const int _kk = (KT) & (NT - 1);                                                     \
    const int _bb = ((KT) & 1) * 16384;                                                  \
    const bf16* _g0 = B + (size_t)(n0 + (H) * 128 + sr) * K_DIM + _kk * 64 + sc;         \
    __builtin_amdgcn_global_load_lds((GLOBAL_AS const void*)_g0,                         \
        (LDS_AS void*)(ldsB + _bb + (H) * 8192 + so), 16, 0, 0);                         \
    const bf16* _g1 = B + (size_t)(n0 + (H) * 128 + 64 + sr) * K_DIM + _kk * 64 + sc;    \
    __builtin_amdgcn_global_load_lds((GLOBAL_AS const void*)_g1,                         \
        (LDS_AS void*)(ldsB + _bb + (H) * 8192 + 4096 + so), 16, 0, 0);                  \
} while (0)

#define LDA(MH, BO) do {                                                                 \
    _Pragma("unroll")                                                                    \
    for (int _i = 0; _i < 4; ++_i) {                                                     \
        const int _r = (BO) + (wrA + (MH) * 64 + _i * 16 + la15) * 64;                   \
        af[0][_i] = *(const bf16x8*)(ldsA + _r + ck0);                                   \
        af[1][_i] = *(const bf16x8*)(ldsA + _r + ck1);                                   \
    }                                                                                    \
} while (0)

#define LDB(NH, DST, BO) do {                                                            \
    _Pragma("unroll")                                                                    \
    for (int _j = 0; _j < 2; ++_j) {                                                     \
        const int _r = (BO) + (wrB + (NH) * 32 + _j * 16 + la15) * 64;                   \
        DST[0][_j] = *(const bf16x8*)(ldsB + _r + ck0);                                  \
        DST[1][_j] = *(const bf16x8*)(ldsB + _r + ck1);                                  \
    }                                                                                    \
} while (0)

#define MMA_BLK(I0, J0, BB) do {                                                         \
    __builtin_amdgcn_s_setprio(1);                                                       \
    _Pragma("unroll")                                                                    \
    for (int _i = 0; _i < 4; ++_i) {                                                     \
        _Pragma("unroll")                                                                \
        for (int _j = 0; _j < 2; ++_j) {                                                 \
            acc[(I0) + _i][(J0) + _j] = __builtin_amdgcn_mfma_f32_16x16x32_bf16(         \
                af[0][_i], BB[0][_j], acc[(I0) + _i][(J0) + _j], 0, 0, 0);               \
            acc[(I0) + _i][(J0) + _j] = __builtin_amdgcn_mfma_f32_16x16x32_bf16(         \
                af[1][_i], BB[1][_j], acc[(I0) + _i][(J0) + _j], 0, 0, 0);               \
        }                                                                                \
    }                                                                                    \
    __builtin_amdgcn_s_setprio(0);                                                       \
} while (0)

#define BAR() __builtin_amdgcn_s_barrier()

    // ---- prologue: tile0 fully + tile1 {B0,A0} in flight ----
    STAGE_A(0, 0); STAGE_B(0, 0); STAGE_A(0, 1); STAGE_B(0, 1);
    STAGE_B(1, 0); STAGE_A(1, 0);
    asm volatile("s_waitcnt vmcnt(4)" ::: "memory");   // tile0 complete, 4 outstanding
    BAR();

    for (int t = 0; t < NT; ++t) {
        const int bo = (t & 1) * 16384;

        // ---- phase 1: quadrant (mh0, nh0) ----
        LDA(0, bo);
        LDB(0, b0, bo);
        STAGE_A(t + 1, 1);
        BAR();
        MMA_BLK(0, 0, b0);
        BAR();

        // ---- phase 2: quadrant (mh0, nh1) ----
        LDB(1, b1, bo);
        STAGE_B(t + 1, 1);
        BAR();
        MMA_BLK(0, 2, b1);
        BAR();

        // ---- phase 3: quadrant (mh1, nh1) ----
        LDA(1, bo);
        STAGE_B(t + 2, 0);
        BAR();
        MMA_BLK(4, 2, b1);
        BAR();

        // ---- phase 4: quadrant (mh1, nh0) ----
        STAGE_A(t + 2, 0);
        BAR();
        MMA_BLK(4, 0, b0);
        asm volatile("s_waitcnt vmcnt(4)" ::: "memory");  // next tile fully staged
        BAR();
    }

    asm volatile("s_waitcnt vmcnt(0)" ::: "memory");  // drain tail stages before exit

    // ---- epilogue: C/D layout col = lane&15 (N), row = (lane>>4)*4 + reg (M) ----
    const int crow = lhi * 4;
#pragma unroll
    for (int j = 0; j < 4; ++j) {
        const int col = n0 + wrB + j * 16 + la15;
        const float s = scales[col];
#pragma unroll
        for (int i = 0; i < 8; ++i) {
            const int rowb = m0 + wrA + i * 16 + crow;
#pragma unroll
            for (int r = 0; r < 4; ++r)
                C[(size_t)(rowb + r) * N_DIM + col] = acc[i][j][r] * s;
        }
    }

#undef STAGE_A
#undef STAGE_B
#undef LDA
#undef LDB
#undef MMA_BLK
#undef BAR
}

// ---------------- fallback: fused conversion staging (no workspace needed) ----------------

__global__ __launch_bounds__(256, 2) void gemm_fused(const float* __restrict__ A,
                                                     const int* __restrict__ B,
                                                     const float* __restrict__ scales,
                                                     float* __restrict__ C) {
    __shared__ bf16 lds_a[128 * 32];
    __shared__ bf16 lds_b[128 * 32];

    const int tid  = threadIdx.x;
    const int wave = tid >> 6;
    const int lane = tid & 63;
    const int m0 = blockIdx.y * 128;
    const int n0 = blockIdx.x * 128;
    const int wm = (wave >> 1) * 64;
    const int wn = (wave & 1) * 64;

    const int sr = tid >> 1;
    const int sc = (tid & 1) * 16;

    const int la = lane & 15;
    const int lk = (lane >> 4) * 8;

    f32x4 acc[4][4] = {};

    for (int k0 = 0; k0 < K_DIM; k0 += 32) {
        __syncthreads();
        {
            const float* ga = A + (size_t)(m0 + sr) * K_DIM + k0 + sc;
            float4 v0 = *(const float4*)(ga + 0);
            float4 v1 = *(const float4*)(ga + 4);
            float4 v2 = *(const float4*)(ga + 8);
            float4 v3 = *(const float4*)(ga + 12);
            bf16x8 p0, p1;
            p0[0]=(bf16)v0.x; p0[1]=(bf16)v0.y; p0[2]=(bf16)v0.z; p0[3]=(bf16)v0.w;
            p0[4]=(bf16)v1.x; p0[5]=(bf16)v1.y; p0[6]=(bf16)v1.z; p0[7]=(bf16)v1.w;
            p1[0]=(bf16)v2.x; p1[1]=(bf16)v2.y; p1[2]=(bf16)v2.z; p1[3]=(bf16)v2.w;
            p1[4]=(bf16)v3.x; p1[5]=(bf16)v3.y; p1[6]=(bf16)v3.z; p1[7]=(bf16)v3.w;
            *(bf16x8*)(lds_a + sr * 32 + sc)     = p0;
            *(bf16x8*)(lds_a + sr * 32 + sc + 8) = p1;
        }
        {
            const int* gb = B + (size_t)(n0 + sr) * K_DIM + k0 + sc;
            int4 v0 = *(const int4*)(gb + 0);
            int4 v1 = *(const int4*)(gb + 4);
            int4 v2 = *(const int4*)(gb + 8);
            int4 v3 = *(const int4*)(gb + 12);
            bf16x8 p0, p1;
            p0[0]=(bf16)(float)v0.x; p0[1]=(bf16)(float)v0.y; p0[2]=(bf16)(float)v0.z; p0[3]=(bf16)(float)v0.w;
            p0[4]=(bf16)(float)v1.x; p0[5]=(bf16)(float)v1.y; p0[6]=(bf16)(float)v1.z; p0[7]=(bf16)(float)v1.w;
            p1[0]=(bf16)(float)v2.x; p1[1]=(bf16)(float)v2.y; p1[2]=(bf16)(float)v2.z; p1[3]=(bf16)(float)v2.w;
            p1[4]=(bf16)(float)v3.x; p1[5]=(bf16)(float)v3.y; p1[6]=(bf16)(float)v3.z; p1[7]=(bf16)(float)v3.w;
            *(bf16x8*)(lds_b + sr * 32 + sc)     = p0;
            *(bf16x8*)(lds_b + sr * 32 + sc + 8) = p1;
        }
        __syncthreads();

        bf16x8 af[4], bfg[4];
#pragma unroll
        for (int i = 0; i < 4; ++i)
            af[i] = *(const bf16x8*)(lds_a + (wm + i * 16 + la) * 32 + lk);
#pragma unroll
        for (int j = 0; j < 4; ++j)
            bfg[j] = *(const bf16x8*)(lds_b + (wn + j * 16 + la) * 32 + lk);
#pragma unroll
        for (int i = 0; i < 4; ++i)
#pragma unroll
            for (int j = 0; j < 4; ++j)
                acc[i][j] = __builtin_amdgcn_mfma_f32_16x16x32_bf16(af[i], bfg[j], acc[i][j], 0, 0, 0);
    }

    const int crow = (lane >> 4) * 4;
#pragma unroll
    for (int j = 0; j < 4; ++j) {
        const int col = n0 + wn + j * 16 + la;
        const float s = scales[col];
#pragma unroll
        for (int i = 0; i < 4; ++i) {
            const int rowb = m0 + wm + i * 16 + crow;
#pragma unroll
            for (int r = 0; r < 4; ++r)
                C[(size_t)(rowb + r) * N_DIM + col] = acc[i][j][r] * s;
        }
    }
}

// ---------------- launch ----------------

extern "C" void kernel_launch(void* const* d_in, const int* in_sizes, int n_in,
                              void* d_out, int out_size, void* d_ws, size_t ws_size,
                              hipStream_t stream) {
    const float* input  = (const float*)d_in[0];   // [M, K] fp32
    const int*   weight = (const int*)d_in[1];     // [N, K] int32 (int8 values)
    const float* scales = (const float*)d_in[2];   // [N] fp32
    float* out = (float*)d_out;                    // [M, N] fp32

    const size_t needA = (size_t)M_DIM * K_DIM * sizeof(bf16);   // 64 MiB
    const size_t needB = (size_t)N_DIM * K_DIM * sizeof(bf16);   // 32 MiB

    if (ws_size >= needA + needB) {
        bf16* Abf = (bf16*)d_ws;
        bf16* Bbf = (bf16*)((char*)d_ws + needA);
        cvt_input_bf16<<<(M_DIM * (size_t)K_DIM / 8) / 256, 256, 0, stream>>>(
            (const float4*)input, (bf16x8*)Abf);
        cvt_weight_bf16<<<(N_DIM * (size_t)K_DIM / 8) / 256, 256, 0, stream>>>(
            (const int4*)weight, (bf16x8*)Bbf);
        gemm_bt_256<<<(M_DIM / 256) * (N_DIM / 256), 512, 0, stream>>>(Abf, Bbf, scales, out);
    } else {
        dim3 grid(N_DIM / 128, M_DIM / 128);
        gemm_fused<<<grid, 256, 0, stream>>>(input, weight, scales, out);
    }
}